// Round 3
// baseline (4063.878 us; speedup 1.0000x reference)
//
#include <hip/hip_runtime.h>

// JANET layer: T=2048, B=64, I=256, H=256.
// Phase 1 (unchanged): xfh[row][0:512] = seq_row @ [W_f|W_h] + [b_f|b_h], fp16 workspace.
// Phase 2: MFMA recurrence.
//   16 batches per block (4 blocks) -> per-step matvec is a 16x256 @ 256x512 GEMM
//   done with mfma_f32_16x16x32_f16: 32 MFMA/wave/step instead of 1024 wave-dot2s
//   (dot2 version was VALU-issue-bound: 57% normalized VALUBusy).
//   Each wave owns the SAME 32-col slice of U_f (acc tiles 0-1) and U_h (tiles 2-3),
//   so f- and g-preacts for one (batch,j) land in the same lane -> no cross-wave
//   exchange, no g_lds, ONE barrier/step with double-buffered fp16 h in LDS.
//   h rows XOR-swizzled (byte ^= (row&7)<<4) so A-frag ds_read_b128 is ~2-way/free
//   (row-major [16][512B] would be a 16-way conflict). Exact f32 h kept in regs.

#define T_STEPS 2048
#define BATCH   64
#define NCOL    512
#define MB      16      // batches per block = MFMA M

typedef _Float16 half_t;
typedef half_t f16x8  __attribute__((ext_vector_type(8)));
typedef half_t half4_t __attribute__((ext_vector_type(4)));
typedef float  f32x4  __attribute__((ext_vector_type(4)));

__device__ __forceinline__ float4 ld4(const float* p) { return *(const float4*)p; }
__device__ __forceinline__ void fma4(float4& acc, float s, const float4& v) {
  acc.x = fmaf(s, v.x, acc.x); acc.y = fmaf(s, v.y, acc.y);
  acc.z = fmaf(s, v.z, acc.z); acc.w = fmaf(s, v.w, acc.w);
}

__device__ __forceinline__ void store_xt(float* p, const float4& v) { *(float4*)p = v; }
__device__ __forceinline__ void store_xt(half_t* p, const float4& v) {
  half4_t h;
  h.x = (half_t)v.x; h.y = (half_t)v.y; h.z = (half_t)v.z; h.w = (half_t)v.w;
  *(half4_t*)p = h;   // 8B store, offsets are multiples of 4 elements
}
__device__ __forceinline__ float xload(const float* p) { return *p; }
__device__ __forceinline__ float xload(const half_t* p) { return (float)*p; }

// ---------------- Phase 1: input-projection GEMM (unchanged) ----------------
template <typename XT>
__global__ __launch_bounds__(256, 4)
void xproj_gemm(const float* __restrict__ seq,
                const float* __restrict__ Wf, const float* __restrict__ bf,
                const float* __restrict__ Wh, const float* __restrict__ bh,
                XT* __restrict__ xfh)
{
  __shared__ float As[32 * 132];   // A^T: [k][m], pitch 132
  __shared__ float Bs[32 * 132];   // B:   [k][n], pitch 132
  const int tid = threadIdx.x;
  const int mt = blockIdx.x >> 2;
  const int nt = blockIdx.x & 3;
  const int m0 = mt * 128;
  const int n0 = nt * 128;
  const int tm = tid >> 4;   // 0..15
  const int tn = tid & 15;   // 0..15

  float4 acc[8][2];
  #pragma unroll
  for (int i = 0; i < 8; ++i) {
    acc[i][0] = make_float4(0.f, 0.f, 0.f, 0.f);
    acc[i][1] = make_float4(0.f, 0.f, 0.f, 0.f);
  }

  const float* bsrc  = (n0 < 256) ? Wf : Wh;
  const int    bcol0 = (n0 < 256) ? n0 : (n0 - 256);

  for (int kt = 0; kt < 8; ++kt) {
    const int k0 = kt * 32;
    #pragma unroll
    for (int p = 0; p < 4; ++p) {
      int idx = p * 256 + tid;
      int r   = idx >> 3;   // 0..127
      int c4  = idx & 7;    // 0..7
      float4 v = ld4(seq + (size_t)(m0 + r) * 256 + k0 + c4 * 4);
      As[(c4*4+0)*132 + r] = v.x;
      As[(c4*4+1)*132 + r] = v.y;
      As[(c4*4+2)*132 + r] = v.z;
      As[(c4*4+3)*132 + r] = v.w;
    }
    #pragma unroll
    for (int p = 0; p < 4; ++p) {
      int idx = p * 256 + tid;
      int kr  = idx >> 5;   // 0..31
      int c4  = idx & 31;   // 0..31
      float4 v = ld4(bsrc + (size_t)(k0 + kr) * 256 + bcol0 + c4 * 4);
      *(float4*)&Bs[kr*132 + c4*4] = v;
    }
    __syncthreads();
    #pragma unroll
    for (int k = 0; k < 32; ++k) {
      float4 a0 = ld4(&As[k*132 + tm*4]);
      float4 a1 = ld4(&As[k*132 + 64 + tm*4]);
      float4 b0 = ld4(&Bs[k*132 + tn*4]);
      float4 b1 = ld4(&Bs[k*132 + 64 + tn*4]);
      float ar[8] = {a0.x, a0.y, a0.z, a0.w, a1.x, a1.y, a1.z, a1.w};
      #pragma unroll
      for (int i = 0; i < 8; ++i) {
        fma4(acc[i][0], ar[i], b0);
        fma4(acc[i][1], ar[i], b1);
      }
    }
    __syncthreads();
  }

  const float* bias_src = (n0 < 256) ? bf : bh;
  float4 bias0 = ld4(bias_src + bcol0 + tn*4);
  float4 bias1 = ld4(bias_src + bcol0 + 64 + tn*4);
  #pragma unroll
  for (int i = 0; i < 8; ++i) {
    int m = m0 + ((i < 4) ? (tm*4 + i) : (64 + tm*4 + (i - 4)));
    float4 r0 = acc[i][0];
    r0.x += bias0.x; r0.y += bias0.y; r0.z += bias0.z; r0.w += bias0.w;
    float4 r1 = acc[i][1];
    r1.x += bias1.x; r1.y += bias1.y; r1.z += bias1.z; r1.w += bias1.w;
    store_xt(xfh + (size_t)m * NCOL + n0 + tn*4,      r0);
    store_xt(xfh + (size_t)m * NCOL + n0 + 64 + tn*4, r1);
  }
}

// ---------------- Phase 2: MFMA recurrence ----------------
// 4 blocks x 512 threads (8 waves). Block handles batches [blockIdx*16, +16).
// Wave w: cols [w*32, w*32+32) of BOTH U_f (acc tiles 0-1) and U_h (tiles 2-3).
// B-frags (U, fp16) persistent in VGPRs: u[4][8] = 128 VGPRs.
// MFMA 16x16x32_f16 layouts: A row = lane&15, k = (lane>>4)*8+e (8 contiguous);
// B col = lane&15, same k; C/D col = lane&15, row(batch) = (lane>>4)*4 + reg.
template <typename XT>
__global__ __launch_bounds__(512, 2)
void janet_rec(const float* __restrict__ Uf, const float* __restrict__ Uh,
               const XT* __restrict__ xfh, const float* __restrict__ pa,
               float* __restrict__ out)
{
  // h double buffer: [2][16 rows][256 cols] fp16, row stride 512B, XOR-swizzled
  __shared__ __align__(16) half_t hbuf[2][MB * 256];
  const int tid  = threadIdx.x;
  const int wave = tid >> 6;
  const int lane = tid & 63;
  const int l15  = lane & 15;
  const int lk   = lane >> 4;          // 0..3
  const int wcol = wave * 32;          // wave's 32-col slice (same j for Uf & Uh)

  // ---- preload B fragments: u[nt][kt]; nt 0-1 = U_f, nt 2-3 = U_h
  f16x8 u[4][8];
  #pragma unroll
  for (int nt = 0; nt < 4; ++nt) {
    const float* Us = (nt < 2) ? Uf : Uh;
    const int col = wcol + (nt & 1) * 16 + l15;
    #pragma unroll
    for (int kt = 0; kt < 8; ++kt) {
      const int k0 = kt * 32 + lk * 8;
      f16x8 v;
      #pragma unroll
      for (int e = 0; e < 8; ++e) v[e] = (half_t)Us[(size_t)(k0 + e) * 256 + col];
      u[nt][kt] = v;
    }
  }

  const float aprelu = pa[0];
  const int b0 = lk * 4;               // C-reg row base (batch within block)

  // zero h buffer 0 (h_{-1} = 0): 512 threads x 8 halves = 4096
  {
    f16x8 z;
    #pragma unroll
    for (int e = 0; e < 8; ++e) z[e] = (half_t)0.f;
    *(f16x8*)&hbuf[0][tid * 8] = z;
  }
  __syncthreads();

  float h_old[2][4];
  #pragma unroll
  for (int n = 0; n < 2; ++n)
    #pragma unroll
    for (int r = 0; r < 4; ++r) h_old[n][r] = 0.f;

  // per-C-row global pointers (x reads, out writes)
  const XT* xp[4];
  float*    op[4];
  #pragma unroll
  for (int r = 0; r < 4; ++r) {
    const int bg = blockIdx.x * MB + b0 + r;
    xp[r] = xfh + (size_t)bg * NCOL + wcol + l15;
    op[r] = out + (size_t)bg * 256  + wcol + l15;
  }

  const char* hb   = (const char*)hbuf;
  const int   swzA = (l15 & 7) << 4;            // A-read swizzle (row = l15)
  const int   arow = l15 * 512 + lk * 16;       // + kt*64, then ^ swzA
  int pb = 0;                                    // current read buffer byte offset

  for (int t = 0; t < T_STEPS; ++t) {
    // x prefetch (hidden under A-read latency + MFMA)
    float xf[2][4], xh[2][4];
    #pragma unroll
    for (int r = 0; r < 4; ++r) {
      xf[0][r] = xload(xp[r] + 0);
      xf[1][r] = xload(xp[r] + 16);
      xh[0][r] = xload(xp[r] + 256);
      xh[1][r] = xload(xp[r] + 272);
      xp[r] += (size_t)BATCH * NCOL;
    }

    // A fragments: 8 x ds_read_b128 (swizzled, ~2-way conflict = free)
    f16x8 a[8];
    #pragma unroll
    for (int kt = 0; kt < 8; ++kt) {
      const int off = pb + ((arow + kt * 64) ^ swzA);
      a[kt] = *(const f16x8*)(hb + off);
    }

    f32x4 acc[4];
    #pragma unroll
    for (int nt = 0; nt < 4; ++nt) {
      acc[nt][0] = 0.f; acc[nt][1] = 0.f; acc[nt][2] = 0.f; acc[nt][3] = 0.f;
    }
    #pragma unroll
    for (int kt = 0; kt < 8; ++kt) {
      #pragma unroll
      for (int nt = 0; nt < 4; ++nt)
        acc[nt] = __builtin_amdgcn_mfma_f32_16x16x32_f16(a[kt], u[nt][kt], acc[nt], 0, 0, 0);
    }

    // combine: f and g for the same (batch, j) live in this lane (tiles n / n+2)
    const int wb = pb ^ (int)sizeof(hbuf[0]);   // 8192
    #pragma unroll
    for (int n = 0; n < 2; ++n) {
      #pragma unroll
      for (int r = 0; r < 4; ++r) {
        const float pf = acc[n][r]     + xf[n][r];
        const float pg = acc[n + 2][r] + xh[n][r];
        const float f  = __builtin_amdgcn_rcpf(1.f + __expf(-pf));          // sigmoid
        const float e2 = __expf(2.f * pg);
        const float g  = 1.f - 2.f * __builtin_amdgcn_rcpf(e2 + 1.f);       // tanh
        float hn = fmaf(f, h_old[n][r] - g, g);                             // f*h+(1-f)*g
        hn = (hn >= 0.f) ? hn : aprelu * hn;                                // prelu
        h_old[n][r] = hn;                                                   // exact f32 state
        op[r][n * 16] = hn;
        const int brow = b0 + r;
        const int woff = wb + ((brow * 512 + (wcol + n * 16 + l15) * 2) ^ ((brow & 7) << 4));
        *(half_t*)((char*)hbuf + woff) = (half_t)hn;                        // fp16 for next A
      }
    }
    #pragma unroll
    for (int r = 0; r < 4; ++r) op[r] += (size_t)BATCH * 256;
    __syncthreads();           // writes of t visible before reads of t+1
    pb = wb;
  }
}

extern "C" void kernel_launch(void* const* d_in, const int* in_sizes, int n_in,
                              void* d_out, int out_size, void* d_ws, size_t ws_size,
                              hipStream_t stream) {
  const float* seq = (const float*)d_in[0];
  const float* Wf  = (const float*)d_in[1];
  const float* Uf  = (const float*)d_in[2];
  const float* bf  = (const float*)d_in[3];
  const float* Wh  = (const float*)d_in[4];
  const float* Uh  = (const float*)d_in[5];
  const float* bh  = (const float*)d_in[6];
  const float* pa  = (const float*)d_in[7];
  float* out = (float*)d_out;

  const size_t rows = (size_t)T_STEPS * BATCH;
  const size_t need_f32 = rows * NCOL * sizeof(float);   // 256 MiB

  dim3 g1(4096), blk1(256);
  dim3 g2(BATCH / MB), blk2(512);

  if (ws_size >= need_f32) {
    float* xfh = (float*)d_ws;
    hipLaunchKernelGGL(xproj_gemm<float>, g1, blk1, 0, stream, seq, Wf, bf, Wh, bh, xfh);
    hipLaunchKernelGGL(janet_rec<float>,  g2, blk2, 0, stream, Uf, Uh, xfh, pa, out);
  } else {
    half_t* xfh = (half_t*)d_ws;
    hipLaunchKernelGGL(xproj_gemm<half_t>, g1, blk1, 0, stream, seq, Wf, bf, Wh, bh, xfh);
    hipLaunchKernelGGL(janet_rec<half_t>,  g2, blk2, 0, stream, Uf, Uh, xfh, pa, out);
  }
}

// Round 4
// 3570.776 us; speedup vs baseline: 1.1381x; 1.1381x over previous
//
#include <hip/hip_runtime.h>

// JANET layer: T=2048, B=64, I=256, H=256.
// Phase 1 (unchanged): xfh[row][0:512] = seq_row @ [W_f|W_h] + [b_f|b_h], fp16 workspace.
// Phase 2: MFMA recurrence, 16 batches/block (4 blocks), U persistent in AGPRs.
//   Round-3 post-mortem: step was ~4100cyc, stall-dominated — the 16 scalar x loads
//   were issued and consumed INSIDE the same step (HBM miss ~900cyc > in-step cover
//   ~350cyc). Fix: depth-2 register prefetch. Two 16-float banks, hand-unrolled x2
//   (static indexing only); at step t the combine reads bank(t&1) and the refill for
//   t+2 immediately reuses that bank (WAR ordering). Loads get ~2 steps of flight.
//   Also: branchless prelu (fmaf(a,min,max)), per-kt A-frag reads (short live ranges).

#define T_STEPS 2048
#define BATCH   64
#define NCOL    512
#define MB      16      // batches per block = MFMA M

typedef _Float16 half_t;
typedef half_t f16x8  __attribute__((ext_vector_type(8)));
typedef half_t half4_t __attribute__((ext_vector_type(4)));
typedef float  f32x4  __attribute__((ext_vector_type(4)));

__device__ __forceinline__ float4 ld4(const float* p) { return *(const float4*)p; }
__device__ __forceinline__ void fma4(float4& acc, float s, const float4& v) {
  acc.x = fmaf(s, v.x, acc.x); acc.y = fmaf(s, v.y, acc.y);
  acc.z = fmaf(s, v.z, acc.z); acc.w = fmaf(s, v.w, acc.w);
}

__device__ __forceinline__ void store_xt(float* p, const float4& v) { *(float4*)p = v; }
__device__ __forceinline__ void store_xt(half_t* p, const float4& v) {
  half4_t h;
  h.x = (half_t)v.x; h.y = (half_t)v.y; h.z = (half_t)v.z; h.w = (half_t)v.w;
  *(half4_t*)p = h;   // 8B store, offsets are multiples of 4 elements
}
__device__ __forceinline__ float xload(const float* p) { return *p; }
__device__ __forceinline__ float xload(const half_t* p) { return (float)*p; }

// ---------------- Phase 1: input-projection GEMM (unchanged) ----------------
template <typename XT>
__global__ __launch_bounds__(256, 4)
void xproj_gemm(const float* __restrict__ seq,
                const float* __restrict__ Wf, const float* __restrict__ bf,
                const float* __restrict__ Wh, const float* __restrict__ bh,
                XT* __restrict__ xfh)
{
  __shared__ float As[32 * 132];   // A^T: [k][m], pitch 132
  __shared__ float Bs[32 * 132];   // B:   [k][n], pitch 132
  const int tid = threadIdx.x;
  const int mt = blockIdx.x >> 2;
  const int nt = blockIdx.x & 3;
  const int m0 = mt * 128;
  const int n0 = nt * 128;
  const int tm = tid >> 4;   // 0..15
  const int tn = tid & 15;   // 0..15

  float4 acc[8][2];
  #pragma unroll
  for (int i = 0; i < 8; ++i) {
    acc[i][0] = make_float4(0.f, 0.f, 0.f, 0.f);
    acc[i][1] = make_float4(0.f, 0.f, 0.f, 0.f);
  }

  const float* bsrc  = (n0 < 256) ? Wf : Wh;
  const int    bcol0 = (n0 < 256) ? n0 : (n0 - 256);

  for (int kt = 0; kt < 8; ++kt) {
    const int k0 = kt * 32;
    #pragma unroll
    for (int p = 0; p < 4; ++p) {
      int idx = p * 256 + tid;
      int r   = idx >> 3;   // 0..127
      int c4  = idx & 7;    // 0..7
      float4 v = ld4(seq + (size_t)(m0 + r) * 256 + k0 + c4 * 4);
      As[(c4*4+0)*132 + r] = v.x;
      As[(c4*4+1)*132 + r] = v.y;
      As[(c4*4+2)*132 + r] = v.z;
      As[(c4*4+3)*132 + r] = v.w;
    }
    #pragma unroll
    for (int p = 0; p < 4; ++p) {
      int idx = p * 256 + tid;
      int kr  = idx >> 5;   // 0..31
      int c4  = idx & 31;   // 0..31
      float4 v = ld4(bsrc + (size_t)(k0 + kr) * 256 + bcol0 + c4 * 4);
      *(float4*)&Bs[kr*132 + c4*4] = v;
    }
    __syncthreads();
    #pragma unroll
    for (int k = 0; k < 32; ++k) {
      float4 a0 = ld4(&As[k*132 + tm*4]);
      float4 a1 = ld4(&As[k*132 + 64 + tm*4]);
      float4 b0 = ld4(&Bs[k*132 + tn*4]);
      float4 b1 = ld4(&Bs[k*132 + 64 + tn*4]);
      float ar[8] = {a0.x, a0.y, a0.z, a0.w, a1.x, a1.y, a1.z, a1.w};
      #pragma unroll
      for (int i = 0; i < 8; ++i) {
        fma4(acc[i][0], ar[i], b0);
        fma4(acc[i][1], ar[i], b1);
      }
    }
    __syncthreads();
  }

  const float* bias_src = (n0 < 256) ? bf : bh;
  float4 bias0 = ld4(bias_src + bcol0 + tn*4);
  float4 bias1 = ld4(bias_src + bcol0 + 64 + tn*4);
  #pragma unroll
  for (int i = 0; i < 8; ++i) {
    int m = m0 + ((i < 4) ? (tm*4 + i) : (64 + tm*4 + (i - 4)));
    float4 r0 = acc[i][0];
    r0.x += bias0.x; r0.y += bias0.y; r0.z += bias0.z; r0.w += bias0.w;
    float4 r1 = acc[i][1];
    r1.x += bias1.x; r1.y += bias1.y; r1.z += bias1.z; r1.w += bias1.w;
    store_xt(xfh + (size_t)m * NCOL + n0 + tn*4,      r0);
    store_xt(xfh + (size_t)m * NCOL + n0 + 64 + tn*4, r1);
  }
}

// ---------------- Phase 2: MFMA recurrence ----------------
// 4 blocks x 512 threads (8 waves). Block handles batches [blockIdx*16, +16).
// Wave w: cols [w*32, w*32+32) of BOTH U_f (acc tiles 0-1) and U_h (tiles 2-3).
// B-frags (U, fp16) persistent: u[4][8] = 128 regs (AGPR half of unified file).
// MFMA 16x16x32_f16: A row = lane&15, k = (lane>>4)*8+e; B col = lane&15;
// C/D col = lane&15, row(batch) = (lane>>4)*4 + reg.
template <typename XT>
__global__ __launch_bounds__(512, 2)
void janet_rec(const float* __restrict__ Uf, const float* __restrict__ Uh,
               const XT* __restrict__ xfh, const float* __restrict__ pa,
               float* __restrict__ out)
{
  // h double buffer: [2][16 rows][256 cols] fp16, row stride 512B, XOR-swizzled
  __shared__ __align__(16) half_t hbuf[2][MB * 256];
  const int tid  = threadIdx.x;
  const int wave = tid >> 6;
  const int lane = tid & 63;
  const int l15  = lane & 15;
  const int lk   = lane >> 4;          // 0..3
  const int wcol = wave * 32;          // wave's 32-col slice (same j for Uf & Uh)

  // ---- preload B fragments: u[nt][kt]; nt 0-1 = U_f, nt 2-3 = U_h
  f16x8 u[4][8];
  #pragma unroll
  for (int nt = 0; nt < 4; ++nt) {
    const float* Us = (nt < 2) ? Uf : Uh;
    const int col = wcol + (nt & 1) * 16 + l15;
    #pragma unroll
    for (int kt = 0; kt < 8; ++kt) {
      const int k0 = kt * 32 + lk * 8;
      f16x8 v;
      #pragma unroll
      for (int e = 0; e < 8; ++e) v[e] = (half_t)Us[(size_t)(k0 + e) * 256 + col];
      u[nt][kt] = v;
    }
  }

  const float aprelu = pa[0];
  const int b0 = lk * 4;               // C-reg row base (batch within block)

  // zero h buffer 0 (h_{-1} = 0): 512 threads x 8 halves = 4096
  {
    f16x8 z;
    #pragma unroll
    for (int e = 0; e < 8; ++e) z[e] = (half_t)0.f;
    *(f16x8*)&hbuf[0][tid * 8] = z;
  }

  float h_old[2][4];
  #pragma unroll
  for (int n = 0; n < 2; ++n)
    #pragma unroll
    for (int r = 0; r < 4; ++r) h_old[n][r] = 0.f;

  // per-C-row global pointers (x reads, out writes)
  const XT* xp[4];
  float*    op[4];
  #pragma unroll
  for (int r = 0; r < 4; ++r) {
    const int bg = blockIdx.x * MB + b0 + r;
    xp[r] = xfh + (size_t)bg * NCOL + wcol + l15;
    op[r] = out + (size_t)bg * 256  + wcol + l15;
  }

  // ---- depth-2 x prefetch: bank slot = r*4 + s, s in {0:xf n0, 1:xf n1, 2:xh n0, 3:xh n1}
  float xbA[16], xbB[16];
  #pragma unroll
  for (int r = 0; r < 4; ++r) {
    xbA[r*4+0] = xload(xp[r] + 0);
    xbA[r*4+1] = xload(xp[r] + 16);
    xbA[r*4+2] = xload(xp[r] + 256);
    xbA[r*4+3] = xload(xp[r] + 272);
    xp[r] += (size_t)BATCH * NCOL;
  }
  #pragma unroll
  for (int r = 0; r < 4; ++r) {
    xbB[r*4+0] = xload(xp[r] + 0);
    xbB[r*4+1] = xload(xp[r] + 16);
    xbB[r*4+2] = xload(xp[r] + 256);
    xbB[r*4+3] = xload(xp[r] + 272);
    xp[r] += (size_t)BATCH * NCOL;   // xp now points at t=2
  }

  const char* hb   = (const char*)hbuf;
  const int   swzA = (l15 & 7) << 4;            // A-read swizzle (row = l15)
  const int   arow = l15 * 512 + lk * 16;       // + kt*64, then ^ swzA
  int pb = 0;                                    // current read buffer byte offset
  __syncthreads();

  // One recurrence step. Reads x from bank xb, then refills xb with step t+2
  // (WAR on xb orders the refill after the last use — ~2 steps of load flight).
#define JSTEP(t, xb)                                                            \
  {                                                                             \
    f32x4 acc[4];                                                               \
    _Pragma("unroll")                                                           \
    for (int nt = 0; nt < 4; ++nt) {                                            \
      acc[nt][0] = 0.f; acc[nt][1] = 0.f; acc[nt][2] = 0.f; acc[nt][3] = 0.f;   \
    }                                                                           \
    _Pragma("unroll")                                                           \
    for (int kt = 0; kt < 8; ++kt) {                                            \
      const int off = pb + ((arow + kt * 64) ^ swzA);                           \
      const f16x8 afrag = *(const f16x8*)(hb + off);                            \
      _Pragma("unroll")                                                         \
      for (int nt = 0; nt < 4; ++nt)                                            \
        acc[nt] = __builtin_amdgcn_mfma_f32_16x16x32_f16(afrag, u[nt][kt],      \
                                                         acc[nt], 0, 0, 0);     \
    }                                                                           \
    const int wb = pb ^ (int)sizeof(hbuf[0]);                                   \
    _Pragma("unroll")                                                           \
    for (int n = 0; n < 2; ++n) {                                               \
      _Pragma("unroll")                                                         \
      for (int r = 0; r < 4; ++r) {                                             \
        const float pf = acc[n][r]     + xb[r*4 + n];                           \
        const float pg = acc[n + 2][r] + xb[r*4 + 2 + n];                       \
        const float f  = __builtin_amdgcn_rcpf(1.f + __expf(-pf));              \
        const float e2 = __expf(2.f * pg);                                      \
        const float g  = 1.f - 2.f * __builtin_amdgcn_rcpf(e2 + 1.f);           \
        float hn = fmaf(f, h_old[n][r] - g, g);                                 \
        hn = fmaf(aprelu, fminf(hn, 0.f), fmaxf(hn, 0.f));   /* prelu */        \
        h_old[n][r] = hn;                                                       \
        op[r][n * 16] = hn;                                                     \
        const int brow = b0 + r;                                                \
        const int woff = wb + ((brow * 512 + (wcol + n * 16 + l15) * 2)         \
                               ^ ((brow & 7) << 4));                            \
        *(half_t*)((char*)hbuf + woff) = (half_t)hn;                            \
      }                                                                         \
    }                                                                           \
    _Pragma("unroll")                                                           \
    for (int r = 0; r < 4; ++r) op[r] += (size_t)BATCH * 256;                   \
    if ((t) + 2 < T_STEPS) {                                                    \
      _Pragma("unroll")                                                         \
      for (int r = 0; r < 4; ++r) {                                             \
        xb[r*4+0] = xload(xp[r] + 0);                                           \
        xb[r*4+1] = xload(xp[r] + 16);                                          \
        xb[r*4+2] = xload(xp[r] + 256);                                         \
        xb[r*4+3] = xload(xp[r] + 272);                                         \
        xp[r] += (size_t)BATCH * NCOL;                                          \
      }                                                                         \
    }                                                                           \
    __syncthreads();                                                            \
    pb = wb;                                                                    \
  }

  for (int t = 0; t < T_STEPS; t += 2) {
    JSTEP(t,     xbA);
    JSTEP(t + 1, xbB);
  }
#undef JSTEP
}

extern "C" void kernel_launch(void* const* d_in, const int* in_sizes, int n_in,
                              void* d_out, int out_size, void* d_ws, size_t ws_size,
                              hipStream_t stream) {
  const float* seq = (const float*)d_in[0];
  const float* Wf  = (const float*)d_in[1];
  const float* Uf  = (const float*)d_in[2];
  const float* bf  = (const float*)d_in[3];
  const float* Wh  = (const float*)d_in[4];
  const float* Uh  = (const float*)d_in[5];
  const float* bh  = (const float*)d_in[6];
  const float* pa  = (const float*)d_in[7];
  float* out = (float*)d_out;

  const size_t rows = (size_t)T_STEPS * BATCH;
  const size_t need_f32 = rows * NCOL * sizeof(float);   // 256 MiB

  dim3 g1(4096), blk1(256);
  dim3 g2(BATCH / MB), blk2(512);

  if (ws_size >= need_f32) {
    float* xfh = (float*)d_ws;
    hipLaunchKernelGGL(xproj_gemm<float>, g1, blk1, 0, stream, seq, Wf, bf, Wh, bh, xfh);
    hipLaunchKernelGGL(janet_rec<float>,  g2, blk2, 0, stream, Uf, Uh, xfh, pa, out);
  } else {
    half_t* xfh = (half_t*)d_ws;
    hipLaunchKernelGGL(xproj_gemm<half_t>, g1, blk1, 0, stream, seq, Wf, bf, Wh, bh, xfh);
    hipLaunchKernelGGL(janet_rec<half_t>,  g2, blk2, 0, stream, Uf, Uh, xfh, pa, out);
  }
}